// Round 7
// baseline (379.936 us; speedup 1.0000x reference)
//
#include <hip/hip_runtime.h>
#include <hip/hip_bf16.h>

#define N_NODES 100000
#define N_EDGES 1600000
#define F_IN 128
#define HID 64
#define NG 128

#define GEMB 1563   // 64-row tiles: ceil(100000/64)
#define DEGB 6250   // ceil(1.6M/256)
#define CNTB 391    // ceil(100K/256)
#define NB   391    // scan blocks over nodes

// 16 fp32 FMAs: acc(4 cols) += xv(4 k-vals) * w0..w3 (rows of W chunk)
#define FMA_ROW(acc, xv) \
    acc.x = fmaf(xv.x, w0.x, acc.x); acc.y = fmaf(xv.x, w0.y, acc.y); \
    acc.z = fmaf(xv.x, w0.z, acc.z); acc.w = fmaf(xv.x, w0.w, acc.w); \
    acc.x = fmaf(xv.y, w1.x, acc.x); acc.y = fmaf(xv.y, w1.y, acc.y); \
    acc.z = fmaf(xv.y, w1.z, acc.z); acc.w = fmaf(xv.y, w1.w, acc.w); \
    acc.x = fmaf(xv.z, w2.x, acc.x); acc.y = fmaf(xv.z, w2.y, acc.y); \
    acc.z = fmaf(xv.z, w2.z, acc.z); acc.w = fmaf(xv.z, w2.w, acc.w); \
    acc.x = fmaf(xv.w, w3.x, acc.x); acc.y = fmaf(xv.w, w3.y, acc.y); \
    acc.z = fmaf(xv.w, w3.z, acc.z); acc.w = fmaf(xv.w, w3.w, acc.w);

#define FMA_EDGE(hh, ww) \
    acc.x = fmaf(hh.x, ww, acc.x); acc.y = fmaf(hh.y, ww, acc.y); \
    acc.z = fmaf(hh.z, ww, acc.z); acc.w = fmaf(hh.w, ww, acc.w);

// ---- 64-row x 64-col GEMM tile, W staged in 16KB LDS halves, X via global ----
template <int K>
__device__ __forceinline__ void gemm_tile(const float* __restrict__ X,
                                          const float* __restrict__ W,
                                          float* __restrict__ H,
                                          int tile, float* smem) {
    const int tid = threadIdx.x;
    const int rg  = tid >> 4;          // 16 row-groups of 4 rows
    const int c4  = (tid & 15) * 4;    // col base
    const int r0  = tile * 64 + rg * 4;
    const bool full = (r0 + 3 < N_NODES);

    float4 a0 = {0,0,0,0}, a1 = {0,0,0,0}, a2 = {0,0,0,0}, a3 = {0,0,0,0};

    for (int kh = 0; kh < K; kh += 64) {
        __syncthreads();
        for (int i = tid; i < 1024; i += 256)
            ((float4*)smem)[i] = ((const float4*)(W + kh * 64))[i];
        __syncthreads();

        const float* Xb = X + (size_t)r0 * K + kh;
        #pragma unroll 4
        for (int k2 = 0; k2 < 64; k2 += 4) {
            float4 w0 = *(float4*)&smem[(k2 + 0) * 64 + c4];
            float4 w1 = *(float4*)&smem[(k2 + 1) * 64 + c4];
            float4 w2 = *(float4*)&smem[(k2 + 2) * 64 + c4];
            float4 w3 = *(float4*)&smem[(k2 + 3) * 64 + c4];
            float4 x0 = {0,0,0,0}, x1 = {0,0,0,0}, x2 = {0,0,0,0}, x3 = {0,0,0,0};
            if (full) {
                x0 = *(const float4*)&Xb[0 * (size_t)K + k2];
                x1 = *(const float4*)&Xb[1 * (size_t)K + k2];
                x2 = *(const float4*)&Xb[2 * (size_t)K + k2];
                x3 = *(const float4*)&Xb[3 * (size_t)K + k2];
            } else {
                if (r0 + 0 < N_NODES) x0 = *(const float4*)&Xb[0 * (size_t)K + k2];
                if (r0 + 1 < N_NODES) x1 = *(const float4*)&Xb[1 * (size_t)K + k2];
                if (r0 + 2 < N_NODES) x2 = *(const float4*)&Xb[2 * (size_t)K + k2];
                if (r0 + 3 < N_NODES) x3 = *(const float4*)&Xb[3 * (size_t)K + k2];
            }
            FMA_ROW(a0, x0);
            FMA_ROW(a1, x1);
            FMA_ROW(a2, x2);
            FMA_ROW(a3, x3);
        }
    }

    if (full) {
        *(float4*)&H[(size_t)(r0 + 0) * 64 + c4] = a0;
        *(float4*)&H[(size_t)(r0 + 1) * 64 + c4] = a1;
        *(float4*)&H[(size_t)(r0 + 2) * 64 + c4] = a2;
        *(float4*)&H[(size_t)(r0 + 3) * 64 + c4] = a3;
    } else {
        if (r0 + 0 < N_NODES) *(float4*)&H[(size_t)(r0 + 0) * 64 + c4] = a0;
        if (r0 + 1 < N_NODES) *(float4*)&H[(size_t)(r0 + 1) * 64 + c4] = a1;
        if (r0 + 2 < N_NODES) *(float4*)&H[(size_t)(r0 + 2) * 64 + c4] = a2;
        if (r0 + 3 < N_NODES) *(float4*)&H[(size_t)(r0 + 3) * 64 + c4] = a3;
    }
}

// ---- merged: degree histogram on dst (stores per-edge rank) + per-graph counts ----
// low VGPR -> high occupancy; latency-bound atomics need wave count (R4/R6 lesson)
__global__ __launch_bounds__(256) void k_degcount(const int* __restrict__ dst,
                                                  int* __restrict__ deg,
                                                  int* __restrict__ rank,
                                                  const int* __restrict__ batch,
                                                  int* __restrict__ gcnt) {
    if (blockIdx.x < DEGB) {
        int e = blockIdx.x * 256 + threadIdx.x;
        if (e < N_EDGES) rank[e] = atomicAdd(&deg[dst[e]], 1);
    } else {
        __shared__ int bins[NG];
        if (threadIdx.x < NG) bins[threadIdx.x] = 0;
        __syncthreads();
        int i = (blockIdx.x - DEGB) * 256 + threadIdx.x;
        if (i < N_NODES) atomicAdd(&bins[batch[i]], 1);
        __syncthreads();
        if (threadIdx.x < NG && bins[threadIdx.x] != 0)
            atomicAdd(&gcnt[threadIdx.x], bins[threadIdx.x]);
    }
}

// ---------------- layer-1 GEMM ----------------
__global__ __launch_bounds__(256) void k_gemm1(const float* __restrict__ X,
                                               const float* __restrict__ W,
                                               float* __restrict__ H) {
    __shared__ float smem[4096];
    gemm_tile<F_IN>(X, W, H, blockIdx.x, smem);
}

// ---------------- scan step 1: per-block sums of deg ----------------
__global__ __launch_bounds__(256) void k_blocksum(const int* __restrict__ deg,
                                                  int* __restrict__ bsum) {
    __shared__ int red[256];
    int i = blockIdx.x * 256 + threadIdx.x;
    red[threadIdx.x] = (i < N_NODES) ? deg[i] : 0;
    __syncthreads();
    for (int off = 128; off > 0; off >>= 1) {
        if (threadIdx.x < off) red[threadIdx.x] += red[threadIdx.x + off];
        __syncthreads();
    }
    if (threadIdx.x == 0) bsum[blockIdx.x] = red[0];
}

// ---------------- scan step 2: exclusive scan of block sums ----------------
__global__ __launch_bounds__(512) void k_scanb(const int* __restrict__ bsum,
                                               int* __restrict__ boff, int nb) {
    __shared__ int tmp[512];
    int t = threadIdx.x;
    int v = (t < nb) ? bsum[t] : 0;
    tmp[t] = v;
    __syncthreads();
    for (int off = 1; off < 512; off <<= 1) {
        int u = (t >= off) ? tmp[t - off] : 0;
        __syncthreads();
        tmp[t] += u;
        __syncthreads();
    }
    if (t < nb) boff[t] = tmp[t] - v;   // exclusive
}

// ---- scan step 3: per-block scan + offset -> rowptr, dinv, invd ----
__global__ __launch_bounds__(256) void k_scanfinal(const int* __restrict__ deg,
                                                   const int* __restrict__ boff,
                                                   int* __restrict__ rowptr,
                                                   float* __restrict__ dinv,
                                                   float* __restrict__ invd) {
    __shared__ int tmp[256];
    int i = blockIdx.x * 256 + threadIdx.x;
    int t = threadIdx.x;
    int v = (i < N_NODES) ? deg[i] : 0;
    tmp[t] = v;
    __syncthreads();
    for (int off = 1; off < 256; off <<= 1) {
        int u = (t >= off) ? tmp[t - off] : 0;
        __syncthreads();
        tmp[t] += u;
        __syncthreads();
    }
    int excl = boff[blockIdx.x] + tmp[t] - v;
    if (i < N_NODES) {
        rowptr[i] = excl;
        float d = (float)v + 1.0f;
        dinv[i] = 1.0f / sqrtf(d);
        invd[i] = 1.0f / d;
    }
    if (blockIdx.x == 0 && t == 0) rowptr[N_NODES] = N_EDGES;
}

// ---- CSR fill, atomic-free, 4B payload: eidx[rowptr[dst]+rank] = src ----
__global__ __launch_bounds__(256) void k_fill(const int* __restrict__ src,
                                              const int* __restrict__ dst,
                                              const int* __restrict__ rank,
                                              const int* __restrict__ rowptr,
                                              int* __restrict__ eidx) {
    int e = blockIdx.x * 256 + threadIdx.x;
    if (e < N_EDGES) {
        eidx[rowptr[dst[e]] + rank[e]] = src[e];
    }
}

// ---- fused gather: out = relu(dinv[d]*sum_e(dinv[s]*h[s]) + h[d]*invd[d] + b) ----
__global__ __launch_bounds__(256) void k_gather(const float* __restrict__ h,
                                                const int* __restrict__ eidx,
                                                const int* __restrict__ rowptr,
                                                const float* __restrict__ dinv,
                                                const float* __restrict__ invd,
                                                const float* __restrict__ bias,
                                                float* __restrict__ outh) {
    int t = blockIdx.x * 256 + threadIdx.x;
    int node = t >> 4;            // 16 threads per node
    int part = t & 15;
    int e0 = rowptr[node], e1 = rowptr[node + 1];

    float4 acc = make_float4(0.f, 0.f, 0.f, 0.f);
    int e = e0;
    for (; e + 7 < e1; e += 8) {
        int s0 = eidx[e],     s1 = eidx[e + 1], s2 = eidx[e + 2], s3 = eidx[e + 3];
        int s4 = eidx[e + 4], s5 = eidx[e + 5], s6 = eidx[e + 6], s7 = eidx[e + 7];
        float w0 = dinv[s0], w1 = dinv[s1], w2 = dinv[s2], w3 = dinv[s3];
        float w4 = dinv[s4], w5 = dinv[s5], w6 = dinv[s6], w7 = dinv[s7];
        float4 h0 = *(const float4*)&h[(size_t)s0 * HID + part * 4];
        float4 h1 = *(const float4*)&h[(size_t)s1 * HID + part * 4];
        float4 h2 = *(const float4*)&h[(size_t)s2 * HID + part * 4];
        float4 h3 = *(const float4*)&h[(size_t)s3 * HID + part * 4];
        float4 h4 = *(const float4*)&h[(size_t)s4 * HID + part * 4];
        float4 h5 = *(const float4*)&h[(size_t)s5 * HID + part * 4];
        float4 h6 = *(const float4*)&h[(size_t)s6 * HID + part * 4];
        float4 h7 = *(const float4*)&h[(size_t)s7 * HID + part * 4];
        FMA_EDGE(h0, w0); FMA_EDGE(h1, w1); FMA_EDGE(h2, w2); FMA_EDGE(h3, w3);
        FMA_EDGE(h4, w4); FMA_EDGE(h5, w5); FMA_EDGE(h6, w6); FMA_EDGE(h7, w7);
    }
    if (e + 3 < e1) {
        int s0 = eidx[e], s1 = eidx[e + 1], s2 = eidx[e + 2], s3 = eidx[e + 3];
        float w0 = dinv[s0], w1 = dinv[s1], w2 = dinv[s2], w3 = dinv[s3];
        float4 h0 = *(const float4*)&h[(size_t)s0 * HID + part * 4];
        float4 h1 = *(const float4*)&h[(size_t)s1 * HID + part * 4];
        float4 h2 = *(const float4*)&h[(size_t)s2 * HID + part * 4];
        float4 h3 = *(const float4*)&h[(size_t)s3 * HID + part * 4];
        FMA_EDGE(h0, w0); FMA_EDGE(h1, w1); FMA_EDGE(h2, w2); FMA_EDGE(h3, w3);
        e += 4;
    }
    for (; e < e1; ++e) {
        int s0 = eidx[e];
        float w0 = dinv[s0];
        float4 h0 = *(const float4*)&h[(size_t)s0 * HID + part * 4];
        FMA_EDGE(h0, w0);
    }

    float di = dinv[node];
    float iv = invd[node];
    float4 hd = *(const float4*)&h[(size_t)node * HID + part * 4];
    float4 b  = *(const float4*)&bias[part * 4];
    float4 r;
    r.x = fmaxf(fmaf(acc.x, di, fmaf(hd.x, iv, b.x)), 0.f);
    r.y = fmaxf(fmaf(acc.y, di, fmaf(hd.y, iv, b.y)), 0.f);
    r.z = fmaxf(fmaf(acc.z, di, fmaf(hd.z, iv, b.z)), 0.f);
    r.w = fmaxf(fmaf(acc.w, di, fmaf(hd.w, iv, b.w)), 0.f);
    *(float4*)&outh[(size_t)node * HID + part * 4] = r;
}

// ---------------- layer-2 GEMM (64x64 tiles, W-only LDS) ----------------
__global__ __launch_bounds__(256) void k_gemmL2(const float* __restrict__ X,
                                                const float* __restrict__ W,
                                                float* __restrict__ H) {
    __shared__ float smem[4096];
    gemm_tile<HID>(X, W, H, blockIdx.x, smem);
}

// ---------------- mean-pool partial sums (batch is sorted) ----------------
__global__ void k_pool(const float* __restrict__ h, const int* __restrict__ batch,
                       float* __restrict__ gsum) {
    int gw = (blockIdx.x * 256 + threadIdx.x) >> 6;  // global wave id
    int lane = threadIdx.x & 63;
    int n0 = gw * 64;
    if (n0 >= N_NODES) return;
    int n1 = min(n0 + 64, N_NODES);
    int gprev = batch[n0];
    float acc = 0.f;
    for (int n = n0; n < n1; ++n) {
        int g = batch[n];
        if (g != gprev) {
            unsafeAtomicAdd(&gsum[gprev * HID + lane], acc);
            acc = 0.f;
            gprev = g;
        }
        acc += h[(size_t)n * HID + lane];
    }
    unsafeAtomicAdd(&gsum[gprev * HID + lane], acc);
}

// ---------------- head: out[g] = (gsum[g]/cnt) . Wout + bout ----------------
__global__ void k_out(const float* __restrict__ gsum, const int* __restrict__ gcnt,
                      const float* __restrict__ Wout, const float* __restrict__ bout,
                      float* __restrict__ out) {
    int g = threadIdx.x;
    if (g >= NG) return;
    float acc = 0.f;
    for (int c = 0; c < HID; ++c) acc += gsum[g * HID + c] * Wout[c];
    float cnt = fmaxf((float)gcnt[g], 1.0f);
    out[g] = acc / cnt + bout[0];
}

extern "C" void kernel_launch(void* const* d_in, const int* in_sizes, int n_in,
                              void* d_out, int out_size, void* d_ws, size_t ws_size,
                              hipStream_t stream) {
    const float* x    = (const float*)d_in[0];
    const int*   ei   = (const int*)d_in[1];
    const int*   batch= (const int*)d_in[2];
    const float* W1   = (const float*)d_in[3];
    const float* b1   = (const float*)d_in[4];
    const float* W2   = (const float*)d_in[5];
    const float* b2   = (const float*)d_in[6];
    const float* Wout = (const float*)d_in[7];
    const float* bout = (const float*)d_in[8];
    float* out = (float*)d_out;

    const int* src  = ei;
    const int* dstp = ei + N_EDGES;

    char* w = (char*)d_ws;
    int*   deg   = (int*)w;    w += (size_t)N_NODES * 4;
    int*   gcnt  = (int*)w;    w += (size_t)NG * 4;
    int*   bsum  = (int*)w;    w += (size_t)NB * 4;
    int*   boff  = (int*)w;    w += (size_t)NB * 4;
    int*   rowptr= (int*)w;    w += (size_t)(N_NODES + 4) * 4;
    float* dinv  = (float*)w;  w += (size_t)N_NODES * 4;
    float* invd  = (float*)w;  w += (size_t)N_NODES * 4;
    float* gsum  = (float*)w;  w += (size_t)NG * HID * 4;
    int*   rank  = (int*)w;    w += (size_t)N_EDGES * 4;
    int*   eidx  = (int*)w;    w += (size_t)N_EDGES * 4;
    float* bufA  = (float*)w;  w += (size_t)N_NODES * HID * 4;
    float* bufB  = (float*)w;  w += (size_t)N_NODES * HID * 4;

    hipMemsetAsync(deg,  0, (size_t)N_NODES * 4, stream);
    hipMemsetAsync(gcnt, 0, (size_t)NG * 4, stream);
    hipMemsetAsync(gsum, 0, (size_t)NG * HID * 4, stream);

    // deg histogram + rank + per-graph counts (high occupancy, 8 VGPR)
    k_degcount <<<DEGB + CNTB, 256, 0, stream>>>(dstp, deg, rank, batch, gcnt);
    // Layer-1 GEMM (independent of CSR build)
    k_gemm1    <<<GEMB, 256, 0, stream>>>(x, W1, bufA);
    // CSR scan + fill
    k_blocksum <<<NB, 256, 0, stream>>>(deg, bsum);
    k_scanb    <<<1, 512, 0, stream>>>(bsum, boff, NB);
    k_scanfinal<<<NB, 256, 0, stream>>>(deg, boff, rowptr, dinv, invd);
    k_fill     <<<(N_EDGES + 255) / 256, 256, 0, stream>>>(src, dstp, rank, rowptr, eidx);

    // Layer 1 aggregation
    k_gather<<<N_NODES * 16 / 256, 256, 0, stream>>>(bufA, eidx, rowptr, dinv, invd, b1, bufB);

    // Layer 2
    k_gemmL2<<<GEMB, 256, 0, stream>>>(bufB, W2, bufA);
    k_gather<<<N_NODES * 16 / 256, 256, 0, stream>>>(bufA, eidx, rowptr, dinv, invd, b2, bufB);

    // Pool + head
    k_pool<<<(N_NODES / 64 + 3) / 4 + 1, 256, 0, stream>>>(bufB, batch, gsum);
    k_out <<<1, 128, 0, stream>>>(gsum, gcnt, Wout, bout, out);
}

// Round 8
// 359.959 us; speedup vs baseline: 1.0555x; 1.0555x over previous
//
#include <hip/hip_runtime.h>
#include <hip/hip_bf16.h>

#define N_NODES 100000
#define N_EDGES 1600000
#define F_IN 128
#define HID 64
#define NG 128

#define GEMB 1563   // 64-row tiles: ceil(100000/64)
#define DEGB 6250   // ceil(1.6M/256)
#define CNTB 391    // ceil(100K/256)
#define NB   391    // scan blocks over nodes

// 16 fp32 FMAs: acc(4 cols) += xv(4 k-vals) * w0..w3 (rows of W chunk)
#define FMA_ROW(acc, xv) \
    acc.x = fmaf(xv.x, w0.x, acc.x); acc.y = fmaf(xv.x, w0.y, acc.y); \
    acc.z = fmaf(xv.x, w0.z, acc.z); acc.w = fmaf(xv.x, w0.w, acc.w); \
    acc.x = fmaf(xv.y, w1.x, acc.x); acc.y = fmaf(xv.y, w1.y, acc.y); \
    acc.z = fmaf(xv.y, w1.z, acc.z); acc.w = fmaf(xv.y, w1.w, acc.w); \
    acc.x = fmaf(xv.z, w2.x, acc.x); acc.y = fmaf(xv.z, w2.y, acc.y); \
    acc.z = fmaf(xv.z, w2.z, acc.z); acc.w = fmaf(xv.z, w2.w, acc.w); \
    acc.x = fmaf(xv.w, w3.x, acc.x); acc.y = fmaf(xv.w, w3.y, acc.y); \
    acc.z = fmaf(xv.w, w3.z, acc.z); acc.w = fmaf(xv.w, w3.w, acc.w);

#define FMA_EDGE(hh, ww) \
    acc.x = fmaf(hh.x, ww, acc.x); acc.y = fmaf(hh.y, ww, acc.y); \
    acc.z = fmaf(hh.z, ww, acc.z); acc.w = fmaf(hh.w, ww, acc.w);

// ---- edge-sum for one (node, part): sum_e dinv[s]*h[s][part*4..+3] ----
__device__ __forceinline__ float4 gather_row(const float* __restrict__ h,
                                             const int* __restrict__ eidx,
                                             const float* __restrict__ dinv,
                                             int e0, int e1, int part) {
    float4 acc = make_float4(0.f, 0.f, 0.f, 0.f);
    int e = e0;
    for (; e + 7 < e1; e += 8) {
        int s0 = eidx[e],     s1 = eidx[e + 1], s2 = eidx[e + 2], s3 = eidx[e + 3];
        int s4 = eidx[e + 4], s5 = eidx[e + 5], s6 = eidx[e + 6], s7 = eidx[e + 7];
        float w0 = dinv[s0], w1 = dinv[s1], w2 = dinv[s2], w3 = dinv[s3];
        float w4 = dinv[s4], w5 = dinv[s5], w6 = dinv[s6], w7 = dinv[s7];
        float4 h0 = *(const float4*)&h[(size_t)s0 * HID + part * 4];
        float4 h1 = *(const float4*)&h[(size_t)s1 * HID + part * 4];
        float4 h2 = *(const float4*)&h[(size_t)s2 * HID + part * 4];
        float4 h3 = *(const float4*)&h[(size_t)s3 * HID + part * 4];
        float4 h4 = *(const float4*)&h[(size_t)s4 * HID + part * 4];
        float4 h5 = *(const float4*)&h[(size_t)s5 * HID + part * 4];
        float4 h6 = *(const float4*)&h[(size_t)s6 * HID + part * 4];
        float4 h7 = *(const float4*)&h[(size_t)s7 * HID + part * 4];
        FMA_EDGE(h0, w0); FMA_EDGE(h1, w1); FMA_EDGE(h2, w2); FMA_EDGE(h3, w3);
        FMA_EDGE(h4, w4); FMA_EDGE(h5, w5); FMA_EDGE(h6, w6); FMA_EDGE(h7, w7);
    }
    if (e + 3 < e1) {
        int s0 = eidx[e], s1 = eidx[e + 1], s2 = eidx[e + 2], s3 = eidx[e + 3];
        float w0 = dinv[s0], w1 = dinv[s1], w2 = dinv[s2], w3 = dinv[s3];
        float4 h0 = *(const float4*)&h[(size_t)s0 * HID + part * 4];
        float4 h1 = *(const float4*)&h[(size_t)s1 * HID + part * 4];
        float4 h2 = *(const float4*)&h[(size_t)s2 * HID + part * 4];
        float4 h3 = *(const float4*)&h[(size_t)s3 * HID + part * 4];
        FMA_EDGE(h0, w0); FMA_EDGE(h1, w1); FMA_EDGE(h2, w2); FMA_EDGE(h3, w3);
        e += 4;
    }
    for (; e < e1; ++e) {
        int s0 = eidx[e];
        float w0 = dinv[s0];
        float4 h0 = *(const float4*)&h[(size_t)s0 * HID + part * 4];
        FMA_EDGE(h0, w0);
    }
    return acc;
}

// ---- 64-row x 64-col GEMM tile, W staged in 16KB LDS halves, X via global ----
template <int K>
__device__ __forceinline__ void gemm_tile(const float* __restrict__ X,
                                          const float* __restrict__ W,
                                          float* __restrict__ H,
                                          int tile, float* smem) {
    const int tid = threadIdx.x;
    const int rg  = tid >> 4;
    const int c4  = (tid & 15) * 4;
    const int r0  = tile * 64 + rg * 4;
    const bool full = (r0 + 3 < N_NODES);

    float4 a0 = {0,0,0,0}, a1 = {0,0,0,0}, a2 = {0,0,0,0}, a3 = {0,0,0,0};

    for (int kh = 0; kh < K; kh += 64) {
        __syncthreads();
        for (int i = tid; i < 1024; i += 256)
            ((float4*)smem)[i] = ((const float4*)(W + kh * 64))[i];
        __syncthreads();

        const float* Xb = X + (size_t)r0 * K + kh;
        #pragma unroll 4
        for (int k2 = 0; k2 < 64; k2 += 4) {
            float4 w0 = *(float4*)&smem[(k2 + 0) * 64 + c4];
            float4 w1 = *(float4*)&smem[(k2 + 1) * 64 + c4];
            float4 w2 = *(float4*)&smem[(k2 + 2) * 64 + c4];
            float4 w3 = *(float4*)&smem[(k2 + 3) * 64 + c4];
            float4 x0 = {0,0,0,0}, x1 = {0,0,0,0}, x2 = {0,0,0,0}, x3 = {0,0,0,0};
            if (full) {
                x0 = *(const float4*)&Xb[0 * (size_t)K + k2];
                x1 = *(const float4*)&Xb[1 * (size_t)K + k2];
                x2 = *(const float4*)&Xb[2 * (size_t)K + k2];
                x3 = *(const float4*)&Xb[3 * (size_t)K + k2];
            } else {
                if (r0 + 0 < N_NODES) x0 = *(const float4*)&Xb[0 * (size_t)K + k2];
                if (r0 + 1 < N_NODES) x1 = *(const float4*)&Xb[1 * (size_t)K + k2];
                if (r0 + 2 < N_NODES) x2 = *(const float4*)&Xb[2 * (size_t)K + k2];
                if (r0 + 3 < N_NODES) x3 = *(const float4*)&Xb[3 * (size_t)K + k2];
            }
            FMA_ROW(a0, x0);
            FMA_ROW(a1, x1);
            FMA_ROW(a2, x2);
            FMA_ROW(a3, x3);
        }
    }

    if (full) {
        *(float4*)&H[(size_t)(r0 + 0) * 64 + c4] = a0;
        *(float4*)&H[(size_t)(r0 + 1) * 64 + c4] = a1;
        *(float4*)&H[(size_t)(r0 + 2) * 64 + c4] = a2;
        *(float4*)&H[(size_t)(r0 + 3) * 64 + c4] = a3;
    } else {
        if (r0 + 0 < N_NODES) *(float4*)&H[(size_t)(r0 + 0) * 64 + c4] = a0;
        if (r0 + 1 < N_NODES) *(float4*)&H[(size_t)(r0 + 1) * 64 + c4] = a1;
        if (r0 + 2 < N_NODES) *(float4*)&H[(size_t)(r0 + 2) * 64 + c4] = a2;
        if (r0 + 3 < N_NODES) *(float4*)&H[(size_t)(r0 + 3) * 64 + c4] = a3;
    }
}

// ---- fused front: [deg histogram + rank | gemm1 tiles | per-graph counts] ----
// (fusion overlap beat separate launches in R6/R7 A/B; hist blocks first)
__global__ __launch_bounds__(256) void k_front(const int* __restrict__ dst,
                                               int* __restrict__ deg,
                                               int* __restrict__ rank,
                                               const int* __restrict__ batch,
                                               int* __restrict__ gcnt,
                                               const float* __restrict__ X,
                                               const float* __restrict__ W,
                                               float* __restrict__ H) {
    __shared__ float smem[4096];   // 16 KB: gemm W-stage / count bins
    int bid = blockIdx.x;
    if (bid < DEGB) {
        int e = bid * 256 + threadIdx.x;
        if (e < N_EDGES) rank[e] = atomicAdd(&deg[dst[e]], 1);
    } else if (bid < DEGB + GEMB) {
        gemm_tile<F_IN>(X, W, H, bid - DEGB, smem);
    } else {
        int* bins = (int*)smem;
        if (threadIdx.x < NG) bins[threadIdx.x] = 0;
        __syncthreads();
        int i = (bid - DEGB - GEMB) * 256 + threadIdx.x;
        if (i < N_NODES) atomicAdd(&bins[batch[i]], 1);
        __syncthreads();
        if (threadIdx.x < NG && bins[threadIdx.x] != 0)
            atomicAdd(&gcnt[threadIdx.x], bins[threadIdx.x]);
    }
}

// ---------------- scan step 1: per-block sums of deg ----------------
__global__ __launch_bounds__(256) void k_blocksum(const int* __restrict__ deg,
                                                  int* __restrict__ bsum) {
    __shared__ int red[256];
    int i = blockIdx.x * 256 + threadIdx.x;
    red[threadIdx.x] = (i < N_NODES) ? deg[i] : 0;
    __syncthreads();
    for (int off = 128; off > 0; off >>= 1) {
        if (threadIdx.x < off) red[threadIdx.x] += red[threadIdx.x + off];
        __syncthreads();
    }
    if (threadIdx.x == 0) bsum[blockIdx.x] = red[0];
}

// ---------------- scan step 2: exclusive scan of block sums ----------------
__global__ __launch_bounds__(512) void k_scanb(const int* __restrict__ bsum,
                                               int* __restrict__ boff, int nb) {
    __shared__ int tmp[512];
    int t = threadIdx.x;
    int v = (t < nb) ? bsum[t] : 0;
    tmp[t] = v;
    __syncthreads();
    for (int off = 1; off < 512; off <<= 1) {
        int u = (t >= off) ? tmp[t - off] : 0;
        __syncthreads();
        tmp[t] += u;
        __syncthreads();
    }
    if (t < nb) boff[t] = tmp[t] - v;   // exclusive
}

// ---- scan step 3: per-block scan + offset -> rowptr, dinv, invd ----
__global__ __launch_bounds__(256) void k_scanfinal(const int* __restrict__ deg,
                                                   const int* __restrict__ boff,
                                                   int* __restrict__ rowptr,
                                                   float* __restrict__ dinv,
                                                   float* __restrict__ invd) {
    __shared__ int tmp[256];
    int i = blockIdx.x * 256 + threadIdx.x;
    int t = threadIdx.x;
    int v = (i < N_NODES) ? deg[i] : 0;
    tmp[t] = v;
    __syncthreads();
    for (int off = 1; off < 256; off <<= 1) {
        int u = (t >= off) ? tmp[t - off] : 0;
        __syncthreads();
        tmp[t] += u;
        __syncthreads();
    }
    int excl = boff[blockIdx.x] + tmp[t] - v;
    if (i < N_NODES) {
        rowptr[i] = excl;
        float d = (float)v + 1.0f;
        dinv[i] = 1.0f / sqrtf(d);
        invd[i] = 1.0f / d;
    }
    if (blockIdx.x == 0 && t == 0) rowptr[N_NODES] = N_EDGES;
}

// ---- CSR fill, atomic-free, 4B payload: eidx[rowptr[dst]+rank] = src ----
__global__ __launch_bounds__(256) void k_fill(const int* __restrict__ src,
                                              const int* __restrict__ dst,
                                              const int* __restrict__ rank,
                                              const int* __restrict__ rowptr,
                                              int* __restrict__ eidx) {
    int e = blockIdx.x * 256 + threadIdx.x;
    if (e < N_EDGES) {
        eidx[rowptr[dst[e]] + rank[e]] = src[e];
    }
}

// ---- fused: gather layer1 (relu agg) -> LDS -> gemm x W2 -> Hout ----
__global__ __launch_bounds__(256) void k_gathergemm(const float* __restrict__ h,
                                                    const int* __restrict__ eidx,
                                                    const int* __restrict__ rowptr,
                                                    const float* __restrict__ dinv,
                                                    const float* __restrict__ invd,
                                                    const float* __restrict__ bias,
                                                    const float* __restrict__ W2,
                                                    float* __restrict__ Hout) {
    __shared__ float Xl[64][66];
    __shared__ float Wl[64 * 64];
    const int tid  = threadIdx.x;
    const int part = tid & 15;
    const int ng4  = tid >> 4;
    const int tile = blockIdx.x;
    const int c4   = part * 4;

    // stage W2 (16KB) while gather loads are in flight
    for (int i = tid; i < 64 * 16; i += 256)
        ((float4*)Wl)[i] = ((const float4*)W2)[i];

    float4 b = *(const float4*)&bias[c4];
    #pragma unroll
    for (int j = 0; j < 4; ++j) {
        int node = tile * 64 + ng4 * 4 + j;
        float4 r = make_float4(0.f, 0.f, 0.f, 0.f);
        if (node < N_NODES) {
            int e0 = rowptr[node], e1 = rowptr[node + 1];
            float4 acc = gather_row(h, eidx, dinv, e0, e1, part);
            float di = dinv[node];
            float iv = invd[node];
            float4 hd = *(const float4*)&h[(size_t)node * HID + c4];
            r.x = fmaxf(fmaf(acc.x, di, fmaf(hd.x, iv, b.x)), 0.f);
            r.y = fmaxf(fmaf(acc.y, di, fmaf(hd.y, iv, b.y)), 0.f);
            r.z = fmaxf(fmaf(acc.z, di, fmaf(hd.z, iv, b.z)), 0.f);
            r.w = fmaxf(fmaf(acc.w, di, fmaf(hd.w, iv, b.w)), 0.f);
        }
        *(float4*)&Xl[ng4 * 4 + j][c4] = r;
    }
    __syncthreads();

    // gemm from LDS: rows rg*4+j, cols c4..c4+3
    float4 a0 = {0,0,0,0}, a1 = {0,0,0,0}, a2 = {0,0,0,0}, a3 = {0,0,0,0};
    #pragma unroll 4
    for (int k2 = 0; k2 < 64; k2 += 4) {
        float4 w0 = *(float4*)&Wl[(k2 + 0) * 64 + c4];
        float4 w1 = *(float4*)&Wl[(k2 + 1) * 64 + c4];
        float4 w2 = *(float4*)&Wl[(k2 + 2) * 64 + c4];
        float4 w3 = *(float4*)&Wl[(k2 + 3) * 64 + c4];
        float4 x0 = *(float4*)&Xl[ng4 * 4 + 0][k2];
        float4 x1 = *(float4*)&Xl[ng4 * 4 + 1][k2];
        float4 x2 = *(float4*)&Xl[ng4 * 4 + 2][k2];
        float4 x3 = *(float4*)&Xl[ng4 * 4 + 3][k2];
        FMA_ROW(a0, x0);
        FMA_ROW(a1, x1);
        FMA_ROW(a2, x2);
        FMA_ROW(a3, x3);
    }

    const int r0 = tile * 64 + ng4 * 4;
    if (r0 + 0 < N_NODES) *(float4*)&Hout[(size_t)(r0 + 0) * 64 + c4] = a0;
    if (r0 + 1 < N_NODES) *(float4*)&Hout[(size_t)(r0 + 1) * 64 + c4] = a1;
    if (r0 + 2 < N_NODES) *(float4*)&Hout[(size_t)(r0 + 2) * 64 + c4] = a2;
    if (r0 + 3 < N_NODES) *(float4*)&Hout[(size_t)(r0 + 3) * 64 + c4] = a3;
}

// ---- fused: gather layer2 (relu agg) -> LDS -> run-length pool -> gsum ----
__global__ __launch_bounds__(256) void k_gatherpool(const float* __restrict__ h,
                                                    const int* __restrict__ eidx,
                                                    const int* __restrict__ rowptr,
                                                    const float* __restrict__ dinv,
                                                    const float* __restrict__ invd,
                                                    const float* __restrict__ bias,
                                                    const int* __restrict__ batch,
                                                    float* __restrict__ gsum) {
    __shared__ float Xl[64][66];
    __shared__ int bl[64];
    const int tid  = threadIdx.x;
    const int part = tid & 15;
    const int ng4  = tid >> 4;
    const int tile = blockIdx.x;
    const int c4   = part * 4;

    if (tid < 64) {
        int node = tile * 64 + tid;
        bl[tid] = (node < N_NODES) ? batch[node] : -1;
    }

    float4 b = *(const float4*)&bias[c4];
    #pragma unroll
    for (int j = 0; j < 4; ++j) {
        int node = tile * 64 + ng4 * 4 + j;
        float4 r = make_float4(0.f, 0.f, 0.f, 0.f);
        if (node < N_NODES) {
            int e0 = rowptr[node], e1 = rowptr[node + 1];
            float4 acc = gather_row(h, eidx, dinv, e0, e1, part);
            float di = dinv[node];
            float iv = invd[node];
            float4 hd = *(const float4*)&h[(size_t)node * HID + c4];
            r.x = fmaxf(fmaf(acc.x, di, fmaf(hd.x, iv, b.x)), 0.f);
            r.y = fmaxf(fmaf(acc.y, di, fmaf(hd.y, iv, b.y)), 0.f);
            r.z = fmaxf(fmaf(acc.z, di, fmaf(hd.z, iv, b.z)), 0.f);
            r.w = fmaxf(fmaf(acc.w, di, fmaf(hd.w, iv, b.w)), 0.f);
        }
        *(float4*)&Xl[ng4 * 4 + j][c4] = r;
    }
    __syncthreads();

    // pool: 64 column-threads, run-length over sorted batch
    if (tid < 64) {
        int c = tid;
        float acc = 0.f;
        int gprev = bl[0];
        #pragma unroll 8
        for (int n = 0; n < 64; ++n) {
            int g = bl[n];
            if (g < 0) break;
            if (g != gprev) {
                unsafeAtomicAdd(&gsum[gprev * HID + c], acc);
                acc = 0.f;
                gprev = g;
            }
            acc += Xl[n][c];
        }
        if (gprev >= 0) unsafeAtomicAdd(&gsum[gprev * HID + c], acc);
    }
}

// ---------------- head: out[g] = (gsum[g]/cnt) . Wout + bout ----------------
__global__ void k_out(const float* __restrict__ gsum, const int* __restrict__ gcnt,
                      const float* __restrict__ Wout, const float* __restrict__ bout,
                      float* __restrict__ out) {
    int g = threadIdx.x;
    if (g >= NG) return;
    float acc = 0.f;
    for (int c = 0; c < HID; ++c) acc += gsum[g * HID + c] * Wout[c];
    float cnt = fmaxf((float)gcnt[g], 1.0f);
    out[g] = acc / cnt + bout[0];
}

extern "C" void kernel_launch(void* const* d_in, const int* in_sizes, int n_in,
                              void* d_out, int out_size, void* d_ws, size_t ws_size,
                              hipStream_t stream) {
    const float* x    = (const float*)d_in[0];
    const int*   ei   = (const int*)d_in[1];
    const int*   batch= (const int*)d_in[2];
    const float* W1   = (const float*)d_in[3];
    const float* b1   = (const float*)d_in[4];
    const float* W2   = (const float*)d_in[5];
    const float* b2   = (const float*)d_in[6];
    const float* Wout = (const float*)d_in[7];
    const float* bout = (const float*)d_in[8];
    float* out = (float*)d_out;

    const int* src  = ei;
    const int* dstp = ei + N_EDGES;

    char* w = (char*)d_ws;
    int*   deg   = (int*)w;    w += (size_t)N_NODES * 4;
    int*   gcnt  = (int*)w;    w += (size_t)NG * 4;
    int*   bsum  = (int*)w;    w += (size_t)NB * 4;
    int*   boff  = (int*)w;    w += (size_t)NB * 4;
    int*   rowptr= (int*)w;    w += (size_t)(N_NODES + 4) * 4;
    float* dinv  = (float*)w;  w += (size_t)N_NODES * 4;
    float* invd  = (float*)w;  w += (size_t)N_NODES * 4;
    float* gsum  = (float*)w;  w += (size_t)NG * HID * 4;
    int*   rank  = (int*)w;    w += (size_t)N_EDGES * 4;
    int*   eidx  = (int*)w;    w += (size_t)N_EDGES * 4;
    float* bufA  = (float*)w;  w += (size_t)N_NODES * HID * 4;
    float* bufB  = (float*)w;  w += (size_t)N_NODES * HID * 4;

    hipMemsetAsync(deg,  0, (size_t)N_NODES * 4, stream);
    hipMemsetAsync(gcnt, 0, (size_t)NG * 4, stream);
    hipMemsetAsync(gsum, 0, (size_t)NG * HID * 4, stream);

    // fused: deg histogram+rank || gemm1 || per-graph counts
    k_front<<<DEGB + GEMB + CNTB, 256, 0, stream>>>(dstp, deg, rank, batch, gcnt,
                                                    x, W1, bufA);
    // CSR scan + fill
    k_blocksum <<<NB, 256, 0, stream>>>(deg, bsum);
    k_scanb    <<<1, 512, 0, stream>>>(bsum, boff, NB);
    k_scanfinal<<<NB, 256, 0, stream>>>(deg, boff, rowptr, dinv, invd);
    k_fill     <<<(N_EDGES + 255) / 256, 256, 0, stream>>>(src, dstp, rank, rowptr, eidx);

    // Layer-1 aggregation fused with layer-2 GEMM
    k_gathergemm<<<GEMB, 256, 0, stream>>>(bufA, eidx, rowptr, dinv, invd, b1, W2, bufB);

    // Layer-2 aggregation fused with mean-pool partials
    k_gatherpool<<<GEMB, 256, 0, stream>>>(bufB, eidx, rowptr, dinv, invd, b2, batch, gsum);

    // head
    k_out<<<1, 128, 0, stream>>>(gsum, gcnt, Wout, bout, out);
}

// Round 9
// 273.653 us; speedup vs baseline: 1.3884x; 1.3154x over previous
//
#include <hip/hip_runtime.h>
#include <hip/hip_fp16.h>

#define N_NODES 100000
#define N_EDGES 1600000
#define F_IN 128
#define HID 64
#define NG 128

#define GEMB 1563   // 64-row tiles: ceil(100000/64)
#define DEGB 6250   // ceil(1.6M/256)
#define CNTB 391    // ceil(100K/256)
#define NB   391    // scan blocks over nodes

// 16 fp32 FMAs: acc(4 cols) += xv(4 k-vals) * w0..w3 (rows of W chunk)
#define FMA_ROW(acc, xv) \
    acc.x = fmaf(xv.x, w0.x, acc.x); acc.y = fmaf(xv.x, w0.y, acc.y); \
    acc.z = fmaf(xv.x, w0.z, acc.z); acc.w = fmaf(xv.x, w0.w, acc.w); \
    acc.x = fmaf(xv.y, w1.x, acc.x); acc.y = fmaf(xv.y, w1.y, acc.y); \
    acc.z = fmaf(xv.y, w1.z, acc.z); acc.w = fmaf(xv.y, w1.w, acc.w); \
    acc.x = fmaf(xv.z, w2.x, acc.x); acc.y = fmaf(xv.z, w2.y, acc.y); \
    acc.z = fmaf(xv.z, w2.z, acc.z); acc.w = fmaf(xv.z, w2.w, acc.w); \
    acc.x = fmaf(xv.w, w3.x, acc.x); acc.y = fmaf(xv.w, w3.y, acc.y); \
    acc.z = fmaf(xv.w, w3.z, acc.z); acc.w = fmaf(xv.w, w3.w, acc.w);

#define FMA_EDGE(hh, ww) \
    acc.x = fmaf(hh.x, ww, acc.x); acc.y = fmaf(hh.y, ww, acc.y); \
    acc.z = fmaf(hh.z, ww, acc.z); acc.w = fmaf(hh.w, ww, acc.w);

#define ADD_EDGE(hh) \
    acc.x += hh.x; acc.y += hh.y; acc.z += hh.z; acc.w += hh.w;

// ---- fp16x4 load/store helpers (8B) ----
__device__ __forceinline__ float4 ldh4(const __half* p) {
    uint2 u = *(const uint2*)p;
    __half2 a = *(__half2*)&u.x, b = *(__half2*)&u.y;
    float2 fa = __half22float2(a), fb = __half22float2(b);
    return make_float4(fa.x, fa.y, fb.x, fb.y);
}
__device__ __forceinline__ void sth4(__half* p, float4 v) {
    __half2 a = __floats2half2_rn(v.x, v.y), b = __floats2half2_rn(v.z, v.w);
    uint2 u; u.x = *(unsigned int*)&a; u.y = *(unsigned int*)&b;
    *(uint2*)p = u;
}

// ---- edge-sum, layer1 (weighted): sum_e dinv[s]*h16[s][c4..c4+3] ----
__device__ __forceinline__ float4 gather_row_w(const __half* __restrict__ h16,
                                               const int* __restrict__ eidx,
                                               const float* __restrict__ dinv,
                                               int e0, int e1, int c4) {
    float4 acc = make_float4(0.f, 0.f, 0.f, 0.f);
    int e = e0;
    for (; e + 7 < e1; e += 8) {
        int s0 = eidx[e],     s1 = eidx[e + 1], s2 = eidx[e + 2], s3 = eidx[e + 3];
        int s4 = eidx[e + 4], s5 = eidx[e + 5], s6 = eidx[e + 6], s7 = eidx[e + 7];
        float w0 = dinv[s0], w1 = dinv[s1], w2 = dinv[s2], w3 = dinv[s3];
        float w4 = dinv[s4], w5 = dinv[s5], w6 = dinv[s6], w7 = dinv[s7];
        float4 h0 = ldh4(&h16[(size_t)s0 * HID + c4]);
        float4 h1 = ldh4(&h16[(size_t)s1 * HID + c4]);
        float4 h2 = ldh4(&h16[(size_t)s2 * HID + c4]);
        float4 h3 = ldh4(&h16[(size_t)s3 * HID + c4]);
        float4 h4 = ldh4(&h16[(size_t)s4 * HID + c4]);
        float4 h5 = ldh4(&h16[(size_t)s5 * HID + c4]);
        float4 h6 = ldh4(&h16[(size_t)s6 * HID + c4]);
        float4 h7 = ldh4(&h16[(size_t)s7 * HID + c4]);
        FMA_EDGE(h0, w0); FMA_EDGE(h1, w1); FMA_EDGE(h2, w2); FMA_EDGE(h3, w3);
        FMA_EDGE(h4, w4); FMA_EDGE(h5, w5); FMA_EDGE(h6, w6); FMA_EDGE(h7, w7);
    }
    if (e + 3 < e1) {
        int s0 = eidx[e], s1 = eidx[e + 1], s2 = eidx[e + 2], s3 = eidx[e + 3];
        float w0 = dinv[s0], w1 = dinv[s1], w2 = dinv[s2], w3 = dinv[s3];
        float4 h0 = ldh4(&h16[(size_t)s0 * HID + c4]);
        float4 h1 = ldh4(&h16[(size_t)s1 * HID + c4]);
        float4 h2 = ldh4(&h16[(size_t)s2 * HID + c4]);
        float4 h3 = ldh4(&h16[(size_t)s3 * HID + c4]);
        FMA_EDGE(h0, w0); FMA_EDGE(h1, w1); FMA_EDGE(h2, w2); FMA_EDGE(h3, w3);
        e += 4;
    }
    for (; e < e1; ++e) {
        int s0 = eidx[e];
        float w0 = dinv[s0];
        float4 h0 = ldh4(&h16[(size_t)s0 * HID + c4]);
        FMA_EDGE(h0, w0);
    }
    return acc;
}

// ---- edge-sum, layer2 (pre-scaled rows): sum_e hw16[s][c4..c4+3] ----
__device__ __forceinline__ float4 gather_row_nw(const __half* __restrict__ h16,
                                                const int* __restrict__ eidx,
                                                int e0, int e1, int c4) {
    float4 acc = make_float4(0.f, 0.f, 0.f, 0.f);
    int e = e0;
    for (; e + 7 < e1; e += 8) {
        int s0 = eidx[e],     s1 = eidx[e + 1], s2 = eidx[e + 2], s3 = eidx[e + 3];
        int s4 = eidx[e + 4], s5 = eidx[e + 5], s6 = eidx[e + 6], s7 = eidx[e + 7];
        float4 h0 = ldh4(&h16[(size_t)s0 * HID + c4]);
        float4 h1 = ldh4(&h16[(size_t)s1 * HID + c4]);
        float4 h2 = ldh4(&h16[(size_t)s2 * HID + c4]);
        float4 h3 = ldh4(&h16[(size_t)s3 * HID + c4]);
        float4 h4 = ldh4(&h16[(size_t)s4 * HID + c4]);
        float4 h5 = ldh4(&h16[(size_t)s5 * HID + c4]);
        float4 h6 = ldh4(&h16[(size_t)s6 * HID + c4]);
        float4 h7 = ldh4(&h16[(size_t)s7 * HID + c4]);
        ADD_EDGE(h0); ADD_EDGE(h1); ADD_EDGE(h2); ADD_EDGE(h3);
        ADD_EDGE(h4); ADD_EDGE(h5); ADD_EDGE(h6); ADD_EDGE(h7);
    }
    if (e + 3 < e1) {
        int s0 = eidx[e], s1 = eidx[e + 1], s2 = eidx[e + 2], s3 = eidx[e + 3];
        float4 h0 = ldh4(&h16[(size_t)s0 * HID + c4]);
        float4 h1 = ldh4(&h16[(size_t)s1 * HID + c4]);
        float4 h2 = ldh4(&h16[(size_t)s2 * HID + c4]);
        float4 h3 = ldh4(&h16[(size_t)s3 * HID + c4]);
        ADD_EDGE(h0); ADD_EDGE(h1); ADD_EDGE(h2); ADD_EDGE(h3);
        e += 4;
    }
    for (; e < e1; ++e) {
        int s0 = eidx[e];
        float4 h0 = ldh4(&h16[(size_t)s0 * HID + c4]);
        ADD_EDGE(h0);
    }
    return acc;
}

// ---- 64x64 GEMM tile -> fp16 output, W staged in 16KB LDS halves ----
template <int K>
__device__ __forceinline__ void gemm_tile(const float* __restrict__ X,
                                          const float* __restrict__ W,
                                          __half* __restrict__ H16,
                                          int tile, float* smem) {
    const int tid = threadIdx.x;
    const int rg  = tid >> 4;
    const int c4  = (tid & 15) * 4;
    const int r0  = tile * 64 + rg * 4;
    const bool full = (r0 + 3 < N_NODES);

    float4 a0 = {0,0,0,0}, a1 = {0,0,0,0}, a2 = {0,0,0,0}, a3 = {0,0,0,0};

    for (int kh = 0; kh < K; kh += 64) {
        __syncthreads();
        for (int i = tid; i < 1024; i += 256)
            ((float4*)smem)[i] = ((const float4*)(W + kh * 64))[i];
        __syncthreads();

        const float* Xb = X + (size_t)r0 * K + kh;
        #pragma unroll 4
        for (int k2 = 0; k2 < 64; k2 += 4) {
            float4 w0 = *(float4*)&smem[(k2 + 0) * 64 + c4];
            float4 w1 = *(float4*)&smem[(k2 + 1) * 64 + c4];
            float4 w2 = *(float4*)&smem[(k2 + 2) * 64 + c4];
            float4 w3 = *(float4*)&smem[(k2 + 3) * 64 + c4];
            float4 x0 = {0,0,0,0}, x1 = {0,0,0,0}, x2 = {0,0,0,0}, x3 = {0,0,0,0};
            if (full) {
                x0 = *(const float4*)&Xb[0 * (size_t)K + k2];
                x1 = *(const float4*)&Xb[1 * (size_t)K + k2];
                x2 = *(const float4*)&Xb[2 * (size_t)K + k2];
                x3 = *(const float4*)&Xb[3 * (size_t)K + k2];
            } else {
                if (r0 + 0 < N_NODES) x0 = *(const float4*)&Xb[0 * (size_t)K + k2];
                if (r0 + 1 < N_NODES) x1 = *(const float4*)&Xb[1 * (size_t)K + k2];
                if (r0 + 2 < N_NODES) x2 = *(const float4*)&Xb[2 * (size_t)K + k2];
                if (r0 + 3 < N_NODES) x3 = *(const float4*)&Xb[3 * (size_t)K + k2];
            }
            FMA_ROW(a0, x0);
            FMA_ROW(a1, x1);
            FMA_ROW(a2, x2);
            FMA_ROW(a3, x3);
        }
    }

    if (full) {
        sth4(&H16[(size_t)(r0 + 0) * HID + c4], a0);
        sth4(&H16[(size_t)(r0 + 1) * HID + c4], a1);
        sth4(&H16[(size_t)(r0 + 2) * HID + c4], a2);
        sth4(&H16[(size_t)(r0 + 3) * HID + c4], a3);
    } else {
        if (r0 + 0 < N_NODES) sth4(&H16[(size_t)(r0 + 0) * HID + c4], a0);
        if (r0 + 1 < N_NODES) sth4(&H16[(size_t)(r0 + 1) * HID + c4], a1);
        if (r0 + 2 < N_NODES) sth4(&H16[(size_t)(r0 + 2) * HID + c4], a2);
        if (r0 + 3 < N_NODES) sth4(&H16[(size_t)(r0 + 3) * HID + c4], a3);
    }
}

// ---- fused front: [gemm1 tiles | deg histogram + rank | per-graph counts] ----
// gemm blocks FIRST (longest-job-first seeding; R6 vs R8 A/B: 112 vs 123 us)
__global__ __launch_bounds__(256) void k_front(const int* __restrict__ dst,
                                               int* __restrict__ deg,
                                               int* __restrict__ rank,
                                               const int* __restrict__ batch,
                                               int* __restrict__ gcnt,
                                               const float* __restrict__ X,
                                               const float* __restrict__ W,
                                               __half* __restrict__ H16) {
    __shared__ float smem[4096];   // 16 KB: gemm W-stage / count bins
    int bid = blockIdx.x;
    if (bid < GEMB) {
        gemm_tile<F_IN>(X, W, H16, bid, smem);
    } else if (bid < GEMB + DEGB) {
        int e = (bid - GEMB) * 256 + threadIdx.x;
        if (e < N_EDGES) rank[e] = atomicAdd(&deg[dst[e]], 1);
    } else {
        int* bins = (int*)smem;
        if (threadIdx.x < NG) bins[threadIdx.x] = 0;
        __syncthreads();
        int i = (bid - GEMB - DEGB) * 256 + threadIdx.x;
        if (i < N_NODES) atomicAdd(&bins[batch[i]], 1);
        __syncthreads();
        if (threadIdx.x < NG && bins[threadIdx.x] != 0)
            atomicAdd(&gcnt[threadIdx.x], bins[threadIdx.x]);
    }
}

// ---------------- scan step 1: per-block sums of deg ----------------
__global__ __launch_bounds__(256) void k_blocksum(const int* __restrict__ deg,
                                                  int* __restrict__ bsum) {
    __shared__ int red[256];
    int i = blockIdx.x * 256 + threadIdx.x;
    red[threadIdx.x] = (i < N_NODES) ? deg[i] : 0;
    __syncthreads();
    for (int off = 128; off > 0; off >>= 1) {
        if (threadIdx.x < off) red[threadIdx.x] += red[threadIdx.x + off];
        __syncthreads();
    }
    if (threadIdx.x == 0) bsum[blockIdx.x] = red[0];
}

// ---------------- scan step 2: exclusive scan of block sums ----------------
__global__ __launch_bounds__(512) void k_scanb(const int* __restrict__ bsum,
                                               int* __restrict__ boff, int nb) {
    __shared__ int tmp[512];
    int t = threadIdx.x;
    int v = (t < nb) ? bsum[t] : 0;
    tmp[t] = v;
    __syncthreads();
    for (int off = 1; off < 512; off <<= 1) {
        int u = (t >= off) ? tmp[t - off] : 0;
        __syncthreads();
        tmp[t] += u;
        __syncthreads();
    }
    if (t < nb) boff[t] = tmp[t] - v;   // exclusive
}

// ---- scan step 3: per-block scan + offset -> rowptr, dinv ----
__global__ __launch_bounds__(256) void k_scanfinal(const int* __restrict__ deg,
                                                   const int* __restrict__ boff,
                                                   int* __restrict__ rowptr,
                                                   float* __restrict__ dinv) {
    __shared__ int tmp[256];
    int i = blockIdx.x * 256 + threadIdx.x;
    int t = threadIdx.x;
    int v = (i < N_NODES) ? deg[i] : 0;
    tmp[t] = v;
    __syncthreads();
    for (int off = 1; off < 256; off <<= 1) {
        int u = (t >= off) ? tmp[t - off] : 0;
        __syncthreads();
        tmp[t] += u;
        __syncthreads();
    }
    int excl = boff[blockIdx.x] + tmp[t] - v;
    if (i < N_NODES) {
        rowptr[i] = excl;
        dinv[i] = 1.0f / sqrtf((float)v + 1.0f);
    }
    if (blockIdx.x == 0 && t == 0) rowptr[N_NODES] = N_EDGES;
}

// ---- CSR fill, atomic-free, 4B payload: eidx[rowptr[dst]+rank] = src ----
__global__ __launch_bounds__(256) void k_fill(const int* __restrict__ src,
                                              const int* __restrict__ dst,
                                              const int* __restrict__ rank,
                                              const int* __restrict__ rowptr,
                                              int* __restrict__ eidx) {
    int e = blockIdx.x * 256 + threadIdx.x;
    if (e < N_EDGES) {
        eidx[rowptr[dst[e]] + rank[e]] = src[e];
    }
}

// ---- fused: gather L1 (fp16 h) -> relu -> LDS -> gemm x W2 -> pre-scaled fp16 ----
__global__ __launch_bounds__(256) void k_gathergemm(const __half* __restrict__ h16,
                                                    const int* __restrict__ eidx,
                                                    const int* __restrict__ rowptr,
                                                    const float* __restrict__ dinv,
                                                    const float* __restrict__ bias,
                                                    const float* __restrict__ W2,
                                                    __half* __restrict__ Hout16) {
    __shared__ float Xl[64][66];
    __shared__ float Wl[64 * 64];
    const int tid  = threadIdx.x;
    const int ng4  = tid >> 4;
    const int tile = blockIdx.x;
    const int c4   = (tid & 15) * 4;

    // stage W2 (16KB) while gather loads are in flight
    for (int i = tid; i < 64 * 16; i += 256)
        ((float4*)Wl)[i] = ((const float4*)W2)[i];

    float4 b = *(const float4*)&bias[c4];
    #pragma unroll
    for (int j = 0; j < 4; ++j) {
        int node = tile * 64 + ng4 * 4 + j;
        float4 r = make_float4(0.f, 0.f, 0.f, 0.f);
        if (node < N_NODES) {
            int e0 = rowptr[node], e1 = rowptr[node + 1];
            float4 acc = gather_row_w(h16, eidx, dinv, e0, e1, c4);
            float di = dinv[node];
            float4 hd = ldh4(&h16[(size_t)node * HID + c4]);
            // z = relu(di*(acc + di*hd) + b)
            r.x = fmaxf(fmaf(di, fmaf(di, hd.x, acc.x), b.x), 0.f);
            r.y = fmaxf(fmaf(di, fmaf(di, hd.y, acc.y), b.y), 0.f);
            r.z = fmaxf(fmaf(di, fmaf(di, hd.z, acc.z), b.z), 0.f);
            r.w = fmaxf(fmaf(di, fmaf(di, hd.w, acc.w), b.w), 0.f);
        }
        *(float4*)&Xl[ng4 * 4 + j][c4] = r;
    }
    __syncthreads();

    // gemm from LDS; epilogue pre-scales by dinv[row] for layer-2 gather
    float4 a0 = {0,0,0,0}, a1 = {0,0,0,0}, a2 = {0,0,0,0}, a3 = {0,0,0,0};
    #pragma unroll 4
    for (int k2 = 0; k2 < 64; k2 += 4) {
        float4 w0 = *(float4*)&Wl[(k2 + 0) * 64 + c4];
        float4 w1 = *(float4*)&Wl[(k2 + 1) * 64 + c4];
        float4 w2 = *(float4*)&Wl[(k2 + 2) * 64 + c4];
        float4 w3 = *(float4*)&Wl[(k2 + 3) * 64 + c4];
        float4 x0 = *(float4*)&Xl[ng4 * 4 + 0][k2];
        float4 x1 = *(float4*)&Xl[ng4 * 4 + 1][k2];
        float4 x2 = *(float4*)&Xl[ng4 * 4 + 2][k2];
        float4 x3 = *(float4*)&Xl[ng4 * 4 + 3][k2];
        FMA_ROW(a0, x0);
        FMA_ROW(a1, x1);
        FMA_ROW(a2, x2);
        FMA_ROW(a3, x3);
    }

    const int r0 = tile * 64 + ng4 * 4;
    if (r0 + 0 < N_NODES) { float d0 = dinv[r0 + 0];
        a0.x *= d0; a0.y *= d0; a0.z *= d0; a0.w *= d0;
        sth4(&Hout16[(size_t)(r0 + 0) * HID + c4], a0); }
    if (r0 + 1 < N_NODES) { float d1 = dinv[r0 + 1];
        a1.x *= d1; a1.y *= d1; a1.z *= d1; a1.w *= d1;
        sth4(&Hout16[(size_t)(r0 + 1) * HID + c4], a1); }
    if (r0 + 2 < N_NODES) { float d2 = dinv[r0 + 2];
        a2.x *= d2; a2.y *= d2; a2.z *= d2; a2.w *= d2;
        sth4(&Hout16[(size_t)(r0 + 2) * HID + c4], a2); }
    if (r0 + 3 < N_NODES) { float d3 = dinv[r0 + 3];
        a3.x *= d3; a3.y *= d3; a3.z *= d3; a3.w *= d3;
        sth4(&Hout16[(size_t)(r0 + 3) * HID + c4], a3); }
}

// ---- fused: gather L2 (pre-scaled fp16) -> relu -> LDS -> run-length pool ----
__global__ __launch_bounds__(256) void k_gatherpool(const __half* __restrict__ hw16,
                                                    const int* __restrict__ eidx,
                                                    const int* __restrict__ rowptr,
                                                    const float* __restrict__ dinv,
                                                    const float* __restrict__ bias,
                                                    const int* __restrict__ batch,
                                                    float* __restrict__ gsum) {
    __shared__ float Xl[64][66];
    __shared__ int bl[64];
    const int tid  = threadIdx.x;
    const int ng4  = tid >> 4;
    const int tile = blockIdx.x;
    const int c4   = (tid & 15) * 4;

    if (tid < 64) {
        int node = tile * 64 + tid;
        bl[tid] = (node < N_NODES) ? batch[node] : -1;
    }

    float4 b = *(const float4*)&bias[c4];
    #pragma unroll
    for (int j = 0; j < 4; ++j) {
        int node = tile * 64 + ng4 * 4 + j;
        float4 r = make_float4(0.f, 0.f, 0.f, 0.f);
        if (node < N_NODES) {
            int e0 = rowptr[node], e1 = rowptr[node + 1];
            float4 acc = gather_row_nw(hw16, eidx, e0, e1, c4);
            float di = dinv[node];
            float4 hw = ldh4(&hw16[(size_t)node * HID + c4]);
            // h2 = relu(di*(acc + hw) + b)   (hw rows are pre-scaled by dinv[src])
            r.x = fmaxf(fmaf(di, acc.x + hw.x, b.x), 0.f);
            r.y = fmaxf(fmaf(di, acc.y + hw.y, b.y), 0.f);
            r.z = fmaxf(fmaf(di, acc.z + hw.z, b.z), 0.f);
            r.w = fmaxf(fmaf(di, acc.w + hw.w, b.w), 0.f);
        }
        *(float4*)&Xl[ng4 * 4 + j][c4] = r;
    }
    __syncthreads();

    // pool: 64 column-threads, run-length over sorted batch
    if (tid < 64) {
        int c = tid;
        float acc = 0.f;
        int gprev = bl[0];
        #pragma unroll 8
        for (int n = 0; n < 64; ++n) {
            int g = bl[n];
            if (g < 0) break;
            if (g != gprev) {
                unsafeAtomicAdd(&gsum[gprev * HID + c], acc);
                acc = 0.f;
                gprev = g;
            }
            acc += Xl[n][c];
        }
        if (gprev >= 0) unsafeAtomicAdd(&gsum[gprev * HID + c], acc);
    }
}

// ---------------- head: out[g] = (gsum[g]/cnt) . Wout + bout ----------------
__global__ void k_out(const float* __restrict__ gsum, const int* __restrict__ gcnt,
                      const float* __restrict__ Wout, const float* __restrict__ bout,
                      float* __restrict__ out) {
    int g = threadIdx.x;
    if (g >= NG) return;
    float acc = 0.f;
    for (int c = 0; c < HID; ++c) acc += gsum[g * HID + c] * Wout[c];
    float cnt = fmaxf((float)gcnt[g], 1.0f);
    out[g] = acc / cnt + bout[0];
}

extern "C" void kernel_launch(void* const* d_in, const int* in_sizes, int n_in,
                              void* d_out, int out_size, void* d_ws, size_t ws_size,
                              hipStream_t stream) {
    const float* x    = (const float*)d_in[0];
    const int*   ei   = (const int*)d_in[1];
    const int*   batch= (const int*)d_in[2];
    const float* W1   = (const float*)d_in[3];
    const float* b1   = (const float*)d_in[4];
    const float* W2   = (const float*)d_in[5];
    const float* b2   = (const float*)d_in[6];
    const float* Wout = (const float*)d_in[7];
    const float* bout = (const float*)d_in[8];
    float* out = (float*)d_out;

    const int* src  = ei;
    const int* dstp = ei + N_EDGES;

    char* w = (char*)d_ws;
    int*    deg   = (int*)w;    w += (size_t)N_NODES * 4;
    int*    gcnt  = (int*)w;    w += (size_t)NG * 4;
    int*    bsum  = (int*)w;    w += (size_t)512 * 4;
    int*    boff  = (int*)w;    w += (size_t)512 * 4;
    int*    rowptr= (int*)w;    w += (size_t)(N_NODES + 4) * 4;
    float*  dinv  = (float*)w;  w += (size_t)N_NODES * 4;
    float*  gsum  = (float*)w;  w += (size_t)NG * HID * 4;
    int*    rank  = (int*)w;    w += (size_t)N_EDGES * 4;
    int*    eidx  = (int*)w;    w += (size_t)N_EDGES * 4;
    __half* bufA16= (__half*)w; w += (size_t)N_NODES * HID * 2;
    __half* bufB16= (__half*)w; w += (size_t)N_NODES * HID * 2;

    hipMemsetAsync(deg,  0, (size_t)N_NODES * 4, stream);
    hipMemsetAsync(gcnt, 0, (size_t)NG * 4, stream);
    hipMemsetAsync(gsum, 0, (size_t)NG * HID * 4, stream);

    // fused: gemm1 (fp16 out) || deg histogram+rank || per-graph counts
    k_front<<<GEMB + DEGB + CNTB, 256, 0, stream>>>(dstp, deg, rank, batch, gcnt,
                                                    x, W1, bufA16);
    // CSR scan + fill
    k_blocksum <<<NB, 256, 0, stream>>>(deg, bsum);
    k_scanb    <<<1, 512, 0, stream>>>(bsum, boff, NB);
    k_scanfinal<<<NB, 256, 0, stream>>>(deg, boff, rowptr, dinv);
    k_fill     <<<(N_EDGES + 255) / 256, 256, 0, stream>>>(src, dstp, rank, rowptr, eidx);

    // Layer-1 aggregation fused with layer-2 GEMM (writes pre-scaled fp16)
    k_gathergemm<<<GEMB, 256, 0, stream>>>(bufA16, eidx, rowptr, dinv, b1, W2, bufB16);

    // Layer-2 aggregation fused with mean-pool partials
    k_gatherpool<<<GEMB, 256, 0, stream>>>(bufB16, eidx, rowptr, dinv, b2, batch, gsum);

    // head
    k_out<<<1, 128, 0, stream>>>(gsum, gcnt, Wout, bout, out);
}

// Round 10
// 272.046 us; speedup vs baseline: 1.3966x; 1.0059x over previous
//
#include <hip/hip_runtime.h>
#include <hip/hip_fp16.h>

#define N_NODES 100000
#define N_EDGES 1600000
#define F_IN 128
#define HID 64
#define NG 128
#define NC 8        // histogram copies (atomic de-contention)

#define GEMB 1563   // 64-row tiles: ceil(100000/64)
#define DEGB 6250   // ceil(1.6M/256)
#define CNTB 391    // ceil(100K/256)
#define NB   391    // scan blocks over nodes

// 16 fp32 FMAs: acc(4 cols) += xv(4 k-vals) * w0..w3 (rows of W chunk)
#define FMA_ROW(acc, xv) \
    acc.x = fmaf(xv.x, w0.x, acc.x); acc.y = fmaf(xv.x, w0.y, acc.y); \
    acc.z = fmaf(xv.x, w0.z, acc.z); acc.w = fmaf(xv.x, w0.w, acc.w); \
    acc.x = fmaf(xv.y, w1.x, acc.x); acc.y = fmaf(xv.y, w1.y, acc.y); \
    acc.z = fmaf(xv.y, w1.z, acc.z); acc.w = fmaf(xv.y, w1.w, acc.w); \
    acc.x = fmaf(xv.z, w2.x, acc.x); acc.y = fmaf(xv.z, w2.y, acc.y); \
    acc.z = fmaf(xv.z, w2.z, acc.z); acc.w = fmaf(xv.z, w2.w, acc.w); \
    acc.x = fmaf(xv.w, w3.x, acc.x); acc.y = fmaf(xv.w, w3.y, acc.y); \
    acc.z = fmaf(xv.w, w3.z, acc.z); acc.w = fmaf(xv.w, w3.w, acc.w);

#define FMA_EDGE(hh, ww) \
    acc.x = fmaf(hh.x, ww, acc.x); acc.y = fmaf(hh.y, ww, acc.y); \
    acc.z = fmaf(hh.z, ww, acc.z); acc.w = fmaf(hh.w, ww, acc.w);

#define ADD_EDGE(hh) \
    acc.x += hh.x; acc.y += hh.y; acc.z += hh.z; acc.w += hh.w;

// ---- fp16x4 load/store helpers (8B) ----
__device__ __forceinline__ float4 ldh4(const __half* p) {
    uint2 u = *(const uint2*)p;
    __half2 a = *(__half2*)&u.x, b = *(__half2*)&u.y;
    float2 fa = __half22float2(a), fb = __half22float2(b);
    return make_float4(fa.x, fa.y, fb.x, fb.y);
}
__device__ __forceinline__ void sth4(__half* p, float4 v) {
    __half2 a = __floats2half2_rn(v.x, v.y), b = __floats2half2_rn(v.z, v.w);
    uint2 u; u.x = *(unsigned int*)&a; u.y = *(unsigned int*)&b;
    *(uint2*)p = u;
}

// ---- edge-sum, layer1 (weighted): sum_e dinv[s]*h16[s][c4..c4+3] ----
__device__ __forceinline__ float4 gather_row_w(const __half* __restrict__ h16,
                                               const int* __restrict__ eidx,
                                               const float* __restrict__ dinv,
                                               int e0, int e1, int c4) {
    float4 acc = make_float4(0.f, 0.f, 0.f, 0.f);
    int e = e0;
    for (; e + 7 < e1; e += 8) {
        int s0 = eidx[e],     s1 = eidx[e + 1], s2 = eidx[e + 2], s3 = eidx[e + 3];
        int s4 = eidx[e + 4], s5 = eidx[e + 5], s6 = eidx[e + 6], s7 = eidx[e + 7];
        float w0 = dinv[s0], w1 = dinv[s1], w2 = dinv[s2], w3 = dinv[s3];
        float w4 = dinv[s4], w5 = dinv[s5], w6 = dinv[s6], w7 = dinv[s7];
        float4 h0 = ldh4(&h16[(size_t)s0 * HID + c4]);
        float4 h1 = ldh4(&h16[(size_t)s1 * HID + c4]);
        float4 h2 = ldh4(&h16[(size_t)s2 * HID + c4]);
        float4 h3 = ldh4(&h16[(size_t)s3 * HID + c4]);
        float4 h4 = ldh4(&h16[(size_t)s4 * HID + c4]);
        float4 h5 = ldh4(&h16[(size_t)s5 * HID + c4]);
        float4 h6 = ldh4(&h16[(size_t)s6 * HID + c4]);
        float4 h7 = ldh4(&h16[(size_t)s7 * HID + c4]);
        FMA_EDGE(h0, w0); FMA_EDGE(h1, w1); FMA_EDGE(h2, w2); FMA_EDGE(h3, w3);
        FMA_EDGE(h4, w4); FMA_EDGE(h5, w5); FMA_EDGE(h6, w6); FMA_EDGE(h7, w7);
    }
    if (e + 3 < e1) {
        int s0 = eidx[e], s1 = eidx[e + 1], s2 = eidx[e + 2], s3 = eidx[e + 3];
        float w0 = dinv[s0], w1 = dinv[s1], w2 = dinv[s2], w3 = dinv[s3];
        float4 h0 = ldh4(&h16[(size_t)s0 * HID + c4]);
        float4 h1 = ldh4(&h16[(size_t)s1 * HID + c4]);
        float4 h2 = ldh4(&h16[(size_t)s2 * HID + c4]);
        float4 h3 = ldh4(&h16[(size_t)s3 * HID + c4]);
        FMA_EDGE(h0, w0); FMA_EDGE(h1, w1); FMA_EDGE(h2, w2); FMA_EDGE(h3, w3);
        e += 4;
    }
    for (; e < e1; ++e) {
        int s0 = eidx[e];
        float w0 = dinv[s0];
        float4 h0 = ldh4(&h16[(size_t)s0 * HID + c4]);
        FMA_EDGE(h0, w0);
    }
    return acc;
}

// ---- edge-sum, layer2 (pre-scaled rows): sum_e hw16[s][c4..c4+3] ----
__device__ __forceinline__ float4 gather_row_nw(const __half* __restrict__ h16,
                                                const int* __restrict__ eidx,
                                                int e0, int e1, int c4) {
    float4 acc = make_float4(0.f, 0.f, 0.f, 0.f);
    int e = e0;
    for (; e + 7 < e1; e += 8) {
        int s0 = eidx[e],     s1 = eidx[e + 1], s2 = eidx[e + 2], s3 = eidx[e + 3];
        int s4 = eidx[e + 4], s5 = eidx[e + 5], s6 = eidx[e + 6], s7 = eidx[e + 7];
        float4 h0 = ldh4(&h16[(size_t)s0 * HID + c4]);
        float4 h1 = ldh4(&h16[(size_t)s1 * HID + c4]);
        float4 h2 = ldh4(&h16[(size_t)s2 * HID + c4]);
        float4 h3 = ldh4(&h16[(size_t)s3 * HID + c4]);
        float4 h4 = ldh4(&h16[(size_t)s4 * HID + c4]);
        float4 h5 = ldh4(&h16[(size_t)s5 * HID + c4]);
        float4 h6 = ldh4(&h16[(size_t)s6 * HID + c4]);
        float4 h7 = ldh4(&h16[(size_t)s7 * HID + c4]);
        ADD_EDGE(h0); ADD_EDGE(h1); ADD_EDGE(h2); ADD_EDGE(h3);
        ADD_EDGE(h4); ADD_EDGE(h5); ADD_EDGE(h6); ADD_EDGE(h7);
    }
    if (e + 3 < e1) {
        int s0 = eidx[e], s1 = eidx[e + 1], s2 = eidx[e + 2], s3 = eidx[e + 3];
        float4 h0 = ldh4(&h16[(size_t)s0 * HID + c4]);
        float4 h1 = ldh4(&h16[(size_t)s1 * HID + c4]);
        float4 h2 = ldh4(&h16[(size_t)s2 * HID + c4]);
        float4 h3 = ldh4(&h16[(size_t)s3 * HID + c4]);
        ADD_EDGE(h0); ADD_EDGE(h1); ADD_EDGE(h2); ADD_EDGE(h3);
        e += 4;
    }
    for (; e < e1; ++e) {
        int s0 = eidx[e];
        float4 h0 = ldh4(&h16[(size_t)s0 * HID + c4]);
        ADD_EDGE(h0);
    }
    return acc;
}

// ---- 64x64 GEMM tile -> fp16 output, W staged in 16KB LDS halves ----
template <int K>
__device__ __forceinline__ void gemm_tile(const float* __restrict__ X,
                                          const float* __restrict__ W,
                                          __half* __restrict__ H16,
                                          int tile, float* smem) {
    const int tid = threadIdx.x;
    const int rg  = tid >> 4;
    const int c4  = (tid & 15) * 4;
    const int r0  = tile * 64 + rg * 4;
    const bool full = (r0 + 3 < N_NODES);

    float4 a0 = {0,0,0,0}, a1 = {0,0,0,0}, a2 = {0,0,0,0}, a3 = {0,0,0,0};

    for (int kh = 0; kh < K; kh += 64) {
        __syncthreads();
        for (int i = tid; i < 1024; i += 256)
            ((float4*)smem)[i] = ((const float4*)(W + kh * 64))[i];
        __syncthreads();

        const float* Xb = X + (size_t)r0 * K + kh;
        #pragma unroll 4
        for (int k2 = 0; k2 < 64; k2 += 4) {
            float4 w0 = *(float4*)&smem[(k2 + 0) * 64 + c4];
            float4 w1 = *(float4*)&smem[(k2 + 1) * 64 + c4];
            float4 w2 = *(float4*)&smem[(k2 + 2) * 64 + c4];
            float4 w3 = *(float4*)&smem[(k2 + 3) * 64 + c4];
            float4 x0 = {0,0,0,0}, x1 = {0,0,0,0}, x2 = {0,0,0,0}, x3 = {0,0,0,0};
            if (full) {
                x0 = *(const float4*)&Xb[0 * (size_t)K + k2];
                x1 = *(const float4*)&Xb[1 * (size_t)K + k2];
                x2 = *(const float4*)&Xb[2 * (size_t)K + k2];
                x3 = *(const float4*)&Xb[3 * (size_t)K + k2];
            } else {
                if (r0 + 0 < N_NODES) x0 = *(const float4*)&Xb[0 * (size_t)K + k2];
                if (r0 + 1 < N_NODES) x1 = *(const float4*)&Xb[1 * (size_t)K + k2];
                if (r0 + 2 < N_NODES) x2 = *(const float4*)&Xb[2 * (size_t)K + k2];
                if (r0 + 3 < N_NODES) x3 = *(const float4*)&Xb[3 * (size_t)K + k2];
            }
            FMA_ROW(a0, x0);
            FMA_ROW(a1, x1);
            FMA_ROW(a2, x2);
            FMA_ROW(a3, x3);
        }
    }

    if (full) {
        sth4(&H16[(size_t)(r0 + 0) * HID + c4], a0);
        sth4(&H16[(size_t)(r0 + 1) * HID + c4], a1);
        sth4(&H16[(size_t)(r0 + 2) * HID + c4], a2);
        sth4(&H16[(size_t)(r0 + 3) * HID + c4], a3);
    } else {
        if (r0 + 0 < N_NODES) sth4(&H16[(size_t)(r0 + 0) * HID + c4], a0);
        if (r0 + 1 < N_NODES) sth4(&H16[(size_t)(r0 + 1) * HID + c4], a1);
        if (r0 + 2 < N_NODES) sth4(&H16[(size_t)(r0 + 2) * HID + c4], a2);
        if (r0 + 3 < N_NODES) sth4(&H16[(size_t)(r0 + 3) * HID + c4], a3);
    }
}

// ---- fused front: [gemm1 | NC-way replicated deg histogram + rank | counts] ----
__global__ __launch_bounds__(256) void k_front(const int* __restrict__ dst,
                                               int* __restrict__ deg8,   // [NC][N]
                                               int* __restrict__ rank,
                                               const int* __restrict__ batch,
                                               int* __restrict__ gcnt,
                                               const float* __restrict__ X,
                                               const float* __restrict__ W,
                                               __half* __restrict__ H16) {
    __shared__ float smem[4096];   // 16 KB: gemm W-stage / count bins
    int bid = blockIdx.x;
    if (bid < GEMB) {
        gemm_tile<F_IN>(X, W, H16, bid, smem);
    } else if (bid < GEMB + DEGB) {
        int hb = bid - GEMB;
        int e = hb * 256 + threadIdx.x;
        int c = hb & (NC - 1);
        if (e < N_EDGES) rank[e] = atomicAdd(&deg8[(size_t)c * N_NODES + dst[e]], 1);
    } else {
        int* bins = (int*)smem;
        if (threadIdx.x < NG) bins[threadIdx.x] = 0;
        __syncthreads();
        int i = (bid - GEMB - DEGB) * 256 + threadIdx.x;
        if (i < N_NODES) atomicAdd(&bins[batch[i]], 1);
        __syncthreads();
        if (threadIdx.x < NG && bins[threadIdx.x] != 0)
            atomicAdd(&gcnt[threadIdx.x], bins[threadIdx.x]);
    }
}

// ---------------- scan step 1: per-block sums of total deg ----------------
__global__ __launch_bounds__(256) void k_blocksum(const int* __restrict__ deg8,
                                                  int* __restrict__ bsum) {
    __shared__ int red[256];
    int i = blockIdx.x * 256 + threadIdx.x;
    int v = 0;
    if (i < N_NODES) {
        #pragma unroll
        for (int c = 0; c < NC; ++c) v += deg8[(size_t)c * N_NODES + i];
    }
    red[threadIdx.x] = v;
    __syncthreads();
    for (int off = 128; off > 0; off >>= 1) {
        if (threadIdx.x < off) red[threadIdx.x] += red[threadIdx.x + off];
        __syncthreads();
    }
    if (threadIdx.x == 0) bsum[blockIdx.x] = red[0];
}

// ---------------- scan step 2: exclusive scan of block sums ----------------
__global__ __launch_bounds__(512) void k_scanb(const int* __restrict__ bsum,
                                               int* __restrict__ boff, int nb) {
    __shared__ int tmp[512];
    int t = threadIdx.x;
    int v = (t < nb) ? bsum[t] : 0;
    tmp[t] = v;
    __syncthreads();
    for (int off = 1; off < 512; off <<= 1) {
        int u = (t >= off) ? tmp[t - off] : 0;
        __syncthreads();
        tmp[t] += u;
        __syncthreads();
    }
    if (t < nb) boff[t] = tmp[t] - v;   // exclusive
}

// ---- scan step 3: per-block scan -> rowptr, dinv, per-copy bases rp2 ----
__global__ __launch_bounds__(256) void k_scanfinal(const int* __restrict__ deg8,
                                                   const int* __restrict__ boff,
                                                   int* __restrict__ rowptr,
                                                   float* __restrict__ dinv,
                                                   int* __restrict__ rp2) {  // [NC][N]
    __shared__ int tmp[256];
    int i = blockIdx.x * 256 + threadIdx.x;
    int t = threadIdx.x;
    int vc[NC];
    int v = 0;
    if (i < N_NODES) {
        #pragma unroll
        for (int c = 0; c < NC; ++c) { vc[c] = deg8[(size_t)c * N_NODES + i]; v += vc[c]; }
    } else {
        #pragma unroll
        for (int c = 0; c < NC; ++c) vc[c] = 0;
    }
    tmp[t] = v;
    __syncthreads();
    for (int off = 1; off < 256; off <<= 1) {
        int u = (t >= off) ? tmp[t - off] : 0;
        __syncthreads();
        tmp[t] += u;
        __syncthreads();
    }
    int excl = boff[blockIdx.x] + tmp[t] - v;
    if (i < N_NODES) {
        rowptr[i] = excl;
        dinv[i] = 1.0f / sqrtf((float)v + 1.0f);
        int run = excl;
        #pragma unroll
        for (int c = 0; c < NC; ++c) { rp2[(size_t)c * N_NODES + i] = run; run += vc[c]; }
    }
    if (blockIdx.x == 0 && t == 0) rowptr[N_NODES] = N_EDGES;
}

// ---- CSR fill, atomic-free: eidx[rp2[c][dst] + rank] = src ----
__global__ __launch_bounds__(256) void k_fill(const int* __restrict__ src,
                                              const int* __restrict__ dst,
                                              const int* __restrict__ rank,
                                              const int* __restrict__ rp2,
                                              int* __restrict__ eidx) {
    int e = blockIdx.x * 256 + threadIdx.x;
    if (e < N_EDGES) {
        int c = (e >> 8) & (NC - 1);
        eidx[rp2[(size_t)c * N_NODES + dst[e]] + rank[e]] = src[e];
    }
}

// ---- fused: gather L1 (fp16 h) -> relu -> LDS -> gemm x W2 -> pre-scaled fp16 ----
__global__ __launch_bounds__(256) void k_gathergemm(const __half* __restrict__ h16,
                                                    const int* __restrict__ eidx,
                                                    const int* __restrict__ rowptr,
                                                    const float* __restrict__ dinv,
                                                    const float* __restrict__ bias,
                                                    const float* __restrict__ W2,
                                                    __half* __restrict__ Hout16) {
    __shared__ float Xl[64][66];
    __shared__ float Wl[64 * 64];
    const int tid  = threadIdx.x;
    const int ng4  = tid >> 4;
    const int tile = blockIdx.x;
    const int c4   = (tid & 15) * 4;

    // stage W2 (16KB) while gather loads are in flight
    for (int i = tid; i < 64 * 16; i += 256)
        ((float4*)Wl)[i] = ((const float4*)W2)[i];

    float4 b = *(const float4*)&bias[c4];
    #pragma unroll
    for (int j = 0; j < 4; ++j) {
        int node = tile * 64 + ng4 * 4 + j;
        float4 r = make_float4(0.f, 0.f, 0.f, 0.f);
        if (node < N_NODES) {
            int e0 = rowptr[node], e1 = rowptr[node + 1];
            float4 acc = gather_row_w(h16, eidx, dinv, e0, e1, c4);
            float di = dinv[node];
            float4 hd = ldh4(&h16[(size_t)node * HID + c4]);
            // z = relu(di*(acc + di*hd) + b)
            r.x = fmaxf(fmaf(di, fmaf(di, hd.x, acc.x), b.x), 0.f);
            r.y = fmaxf(fmaf(di, fmaf(di, hd.y, acc.y), b.y), 0.f);
            r.z = fmaxf(fmaf(di, fmaf(di, hd.z, acc.z), b.z), 0.f);
            r.w = fmaxf(fmaf(di, fmaf(di, hd.w, acc.w), b.w), 0.f);
        }
        *(float4*)&Xl[ng4 * 4 + j][c4] = r;
    }
    __syncthreads();

    // gemm from LDS; epilogue pre-scales by dinv[row] for layer-2 gather
    float4 a0 = {0,0,0,0}, a1 = {0,0,0,0}, a2 = {0,0,0,0}, a3 = {0,0,0,0};
    #pragma unroll 4
    for (int k2 = 0; k2 < 64; k2 += 4) {
        float4 w0 = *(float4*)&Wl[(k2 + 0) * 64 + c4];
        float4 w1 = *(float4*)&Wl[(k2 + 1) * 64 + c4];
        float4 w2 = *(float4*)&Wl[(k2 + 2) * 64 + c4];
        float4 w3 = *(float4*)&Wl[(k2 + 3) * 64 + c4];
        float4 x0 = *(float4*)&Xl[ng4 * 4 + 0][k2];
        float4 x1 = *(float4*)&Xl[ng4 * 4 + 1][k2];
        float4 x2 = *(float4*)&Xl[ng4 * 4 + 2][k2];
        float4 x3 = *(float4*)&Xl[ng4 * 4 + 3][k2];
        FMA_ROW(a0, x0);
        FMA_ROW(a1, x1);
        FMA_ROW(a2, x2);
        FMA_ROW(a3, x3);
    }

    const int r0 = tile * 64 + ng4 * 4;
    if (r0 + 0 < N_NODES) { float d0 = dinv[r0 + 0];
        a0.x *= d0; a0.y *= d0; a0.z *= d0; a0.w *= d0;
        sth4(&Hout16[(size_t)(r0 + 0) * HID + c4], a0); }
    if (r0 + 1 < N_NODES) { float d1 = dinv[r0 + 1];
        a1.x *= d1; a1.y *= d1; a1.z *= d1; a1.w *= d1;
        sth4(&Hout16[(size_t)(r0 + 1) * HID + c4], a1); }
    if (r0 + 2 < N_NODES) { float d2 = dinv[r0 + 2];
        a2.x *= d2; a2.y *= d2; a2.z *= d2; a2.w *= d2;
        sth4(&Hout16[(size_t)(r0 + 2) * HID + c4], a2); }
    if (r0 + 3 < N_NODES) { float d3 = dinv[r0 + 3];
        a3.x *= d3; a3.y *= d3; a3.z *= d3; a3.w *= d3;
        sth4(&Hout16[(size_t)(r0 + 3) * HID + c4], a3); }
}

// ---- fused: gather L2 (pre-scaled fp16) -> relu -> LDS -> run-length pool ----
__global__ __launch_bounds__(256) void k_gatherpool(const __half* __restrict__ hw16,
                                                    const int* __restrict__ eidx,
                                                    const int* __restrict__ rowptr,
                                                    const float* __restrict__ dinv,
                                                    const float* __restrict__ bias,
                                                    const int* __restrict__ batch,
                                                    float* __restrict__ gsum) {
    __shared__ float Xl[64][66];
    __shared__ int bl[64];
    const int tid  = threadIdx.x;
    const int ng4  = tid >> 4;
    const int tile = blockIdx.x;
    const int c4   = (tid & 15) * 4;

    if (tid < 64) {
        int node = tile * 64 + tid;
        bl[tid] = (node < N_NODES) ? batch[node] : -1;
    }

    float4 b = *(const float4*)&bias[c4];
    #pragma unroll
    for (int j = 0; j < 4; ++j) {
        int node = tile * 64 + ng4 * 4 + j;
        float4 r = make_float4(0.f, 0.f, 0.f, 0.f);
        if (node < N_NODES) {
            int e0 = rowptr[node], e1 = rowptr[node + 1];
            float4 acc = gather_row_nw(hw16, eidx, e0, e1, c4);
            float di = dinv[node];
            float4 hw = ldh4(&hw16[(size_t)node * HID + c4]);
            // h2 = relu(di*(acc + hw) + b)   (hw rows are pre-scaled by dinv[src])
            r.x = fmaxf(fmaf(di, acc.x + hw.x, b.x), 0.f);
            r.y = fmaxf(fmaf(di, acc.y + hw.y, b.y), 0.f);
            r.z = fmaxf(fmaf(di, acc.z + hw.z, b.z), 0.f);
            r.w = fmaxf(fmaf(di, acc.w + hw.w, b.w), 0.f);
        }
        *(float4*)&Xl[ng4 * 4 + j][c4] = r;
    }
    __syncthreads();

    // pool: 64 column-threads, run-length over sorted batch
    if (tid < 64) {
        int c = tid;
        float acc = 0.f;
        int gprev = bl[0];
        #pragma unroll 8
        for (int n = 0; n < 64; ++n) {
            int g = bl[n];
            if (g < 0) break;
            if (g != gprev) {
                unsafeAtomicAdd(&gsum[gprev * HID + c], acc);
                acc = 0.f;
                gprev = g;
            }
            acc += Xl[n][c];
        }
        if (gprev >= 0) unsafeAtomicAdd(&gsum[gprev * HID + c], acc);
    }
}

// ---------------- head: out[g] = (gsum[g]/cnt) . Wout + bout ----------------
__global__ void k_out(const float* __restrict__ gsum, const int* __restrict__ gcnt,
                      const float* __restrict__ Wout, const float* __restrict__ bout,
                      float* __restrict__ out) {
    int g = threadIdx.x;
    if (g >= NG) return;
    float acc = 0.f;
    for (int c = 0; c < HID; ++c) acc += gsum[g * HID + c] * Wout[c];
    float cnt = fmaxf((float)gcnt[g], 1.0f);
    out[g] = acc / cnt + bout[0];
}

extern "C" void kernel_launch(void* const* d_in, const int* in_sizes, int n_in,
                              void* d_out, int out_size, void* d_ws, size_t ws_size,
                              hipStream_t stream) {
    const float* x    = (const float*)d_in[0];
    const int*   ei   = (const int*)d_in[1];
    const int*   batch= (const int*)d_in[2];
    const float* W1   = (const float*)d_in[3];
    const float* b1   = (const float*)d_in[4];
    const float* W2   = (const float*)d_in[5];
    const float* b2   = (const float*)d_in[6];
    const float* Wout = (const float*)d_in[7];
    const float* bout = (const float*)d_in[8];
    float* out = (float*)d_out;

    const int* src  = ei;
    const int* dstp = ei + N_EDGES;

    char* w = (char*)d_ws;
    int*    deg8  = (int*)w;    w += (size_t)NC * N_NODES * 4;
    int*    rp2   = (int*)w;    w += (size_t)NC * N_NODES * 4;
    int*    gcnt  = (int*)w;    w += (size_t)NG * 4;
    int*    bsum  = (int*)w;    w += (size_t)512 * 4;
    int*    boff  = (int*)w;    w += (size_t)512 * 4;
    int*    rowptr= (int*)w;    w += (size_t)(N_NODES + 4) * 4;
    float*  dinv  = (float*)w;  w += (size_t)N_NODES * 4;
    float*  gsum  = (float*)w;  w += (size_t)NG * HID * 4;
    int*    rank  = (int*)w;    w += (size_t)N_EDGES * 4;
    int*    eidx  = (int*)w;    w += (size_t)N_EDGES * 4;
    __half* bufA16= (__half*)w; w += (size_t)N_NODES * HID * 2;
    __half* bufB16= (__half*)w; w += (size_t)N_NODES * HID * 2;

    hipMemsetAsync(deg8, 0, (size_t)NC * N_NODES * 4, stream);
    hipMemsetAsync(gcnt, 0, (size_t)NG * 4, stream);
    hipMemsetAsync(gsum, 0, (size_t)NG * HID * 4, stream);

    // fused: gemm1 (fp16 out) || NC-way deg histogram+rank || per-graph counts
    k_front<<<GEMB + DEGB + CNTB, 256, 0, stream>>>(dstp, deg8, rank, batch, gcnt,
                                                    x, W1, bufA16);
    // CSR scan + fill
    k_blocksum <<<NB, 256, 0, stream>>>(deg8, bsum);
    k_scanb    <<<1, 512, 0, stream>>>(bsum, boff, NB);
    k_scanfinal<<<NB, 256, 0, stream>>>(deg8, boff, rowptr, dinv, rp2);
    k_fill     <<<(N_EDGES + 255) / 256, 256, 0, stream>>>(src, dstp, rank, rp2, eidx);

    // Layer-1 aggregation fused with layer-2 GEMM (writes pre-scaled fp16)
    k_gathergemm<<<GEMB, 256, 0, stream>>>(bufA16, eidx, rowptr, dinv, b1, W2, bufB16);

    // Layer-2 aggregation fused with mean-pool partials
    k_gatherpool<<<GEMB, 256, 0, stream>>>(bufB16, eidx, rowptr, dinv, b2, batch, gsum);

    // head
    k_out<<<1, 128, 0, stream>>>(gsum, gcnt, Wout, bout, out);
}